// Round 5
// baseline (332.771 us; speedup 1.0000x reference)
//
#include <hip/hip_runtime.h>

#define B  8
#define N  8192
#define M  2048
#define C  64
#define CT 64
#define K  32
#define R2 0.04f   // nearest f32 to 0.2*0.2, matches jnp/np promotion

// clang-native vector types (kept from R3/R4; plain loads/stores this round)
typedef __attribute__((ext_vector_type(4))) float f4;
typedef __attribute__((ext_vector_type(4))) int   i4;

__device__ __forceinline__ float rfl(float x) {
    union { float f; int i; } u;
    u.f = x;
    u.i = __builtin_amdgcn_readfirstlane(u.i);
    return u.f;
}

// one 64-point chunk. d2 replicates np op order exactly:
// (cn + pn) - 2*cross, no fma contraction. pn^2 precomputed in vv.w.
// Verbatim (correctness-verified since R0). Extra invocations after
// cnt >= K are no-ops (slot >= K never writes), so exit granularity is
// semantics-free.
#define PROC(vv, nn)                                                          \
    do {                                                                      \
        const float cross = __fadd_rn(                                        \
            __fadd_rn(__fmul_rn(cx, (vv).x), __fmul_rn(cy, (vv).y)),          \
            __fmul_rn(cz, (vv).z));                                           \
        const float d2 = __fsub_rn(__fadd_rn(cn, (vv).w),                     \
                                   __fmul_rn(2.0f, cross));                   \
        const bool valid = d2 < R2;                                           \
        const unsigned long long mask = __ballot(valid);                      \
        if (valid) {                                                          \
            const int slot = cnt + __builtin_amdgcn_mbcnt_hi(                 \
                (unsigned)(mask >> 32),                                       \
                __builtin_amdgcn_mbcnt_lo((unsigned)mask, 0));                \
            if (slot < K) snp[slot] = (nn);                                   \
        }                                                                     \
        cnt += (int)__popcll(mask);                                           \
    } while (0)

// ---------------------------------------------------------------------------
// Kernel 1: ball query, whole batch point cloud staged in LDS (R4 structure,
// passed absmax 0.0). ONLY change this round: coord/idx stores are plain
// (nontemporal flag dropped — single-variable A/B vs R4).
// ---------------------------------------------------------------------------
__global__ __launch_bounds__(512) void ballquery_kernel(
    const float* __restrict__ points,   // [B,3,N]
    const float* __restrict__ centers,  // [B,3,M]
    int* __restrict__ idx,              // [B,M,K]
    float* __restrict__ out1)           // [B,67,M,K] (writes ch 0..2)
{
    __shared__ float4 pts4[N];          // 128 KB
    __shared__ int    sn[64 * K];       // 8 KB, one row per local center

    const int bid = blockIdx.x;
    const int b   = bid & 7;            // XCD affinity
    const int m0  = (bid >> 3) << 6;    // 64 centers per block
    const int t   = threadIdx.x;

    // ---- stage the point cloud (coalesced; 32 blocks/batch share L2) ----
    {
        const float* pc = points + (size_t)b * 3 * N;
        #pragma unroll
        for (int i = 0; i < 16; ++i) {
            const int n = i * 512 + t;
            const float px = pc[n];
            const float py = pc[N + n];
            const float pz = pc[2 * N + n];
            float4 v;
            v.x = px; v.y = py; v.z = pz;
            v.w = __fadd_rn(__fadd_rn(__fmul_rn(px, px), __fmul_rn(py, py)),
                            __fmul_rn(pz, pz));   // pn^2, np op order
            pts4[n] = v;
        }
    }
    __syncthreads();

    const int wv   = t >> 6;
    const int lane = t & 63;
    const size_t cs = (size_t)M * K;

    for (int k = 0; k < 8; ++k) {
        const int ml = wv * 8 + k;      // local center 0..63
        const int m  = m0 + ml;

        const float cx = rfl(centers[((size_t)b * 3 + 0) * M + m]);
        const float cy = rfl(centers[((size_t)b * 3 + 1) * M + m]);
        const float cz = rfl(centers[((size_t)b * 3 + 2) * M + m]);
        const float cn = rfl(__fadd_rn(
            __fadd_rn(__fmul_rn(cx, cx), __fmul_rn(cy, cy)),
            __fmul_rn(cz, cz)));

        int* snp = &sn[ml * K];
        if (lane == 0) snp[0] = 0;      // default fill for empty ball
        int cnt = 0;

        // scan 128 chunks of 64 points, early-exit check every 256 points
        for (int c = 0; c < 128; c += 4) {
            const float4 v0 = pts4[(c + 0) * 64 + lane];
            const float4 v1 = pts4[(c + 1) * 64 + lane];
            const float4 v2 = pts4[(c + 2) * 64 + lane];
            const float4 v3 = pts4[(c + 3) * 64 + lane];
            PROC(v0, (c + 0) * 64 + lane);
            PROC(v1, (c + 1) * 64 + lane);
            PROC(v2, (c + 2) * 64 + lane);
            PROC(v3, (c + 3) * 64 + lane);
            if (cnt >= K) break;
        }

        // fill slots >= cnt with first valid index (same-wave LDS ordering,
        // identical to the verified kernel), then emit idx + coord channels.
        if (lane < K) {
            const int fill = snp[0];
            const int v    = snp[lane];
            const int nf   = (lane < cnt) ? v : fill;
            idx[((size_t)b * M + m) * K + lane] = nf;

            const float4 p = pts4[nf];
            const size_t o = (size_t)b * 67 * cs + (size_t)m * K + lane;
            out1[o]          = p.x - cx;
            out1[o + cs]     = p.y - cy;
            out1[o + 2 * cs] = p.z - cz;
        }
    }
}

// ---------------------------------------------------------------------------
// Kernel 2: channel-slab gather (R3/R4 structure, passed absmax 0.0).
// ONLY change this round: all loads/stores plain (nontemporal dropped) —
// testing whether nt-flagged stores forfeit L2 write-combining and cost
// ~10 us across the 274 MB output stream (R0's normal-store fused kernel
// was the session's best per-work number).
// ---------------------------------------------------------------------------
__global__ __launch_bounds__(512) void gather_kernel(
    const float* __restrict__ temb,     // [B,64,N] natural layout
    const float* __restrict__ feats,    // [B,64,N] natural layout
    const int*   __restrict__ idx,      // [B,M,K]
    float* __restrict__ out1,           // [B,67,M,K] (writes ch 3..66)
    float* __restrict__ out2)           // [B,64,M,K]
{
    __shared__ float row[2 * N];        // 64 KB: two channel rows

    const int bid  = blockIdx.x;
    const int b    = bid & 7;           // XCD affinity (idx[b] hot in XCD-b L2)
    const int slab = bid >> 3;          // 0..63
    const int tab  = slab >> 5;         // 0: feats, 1: temb
    const int c0   = (slab & 31) * 2;   // channel pair
    const int t    = threadIdx.x;

    // stage: channels c0,c0+1 are contiguous in [64][N] layout -> linear copy
    const f4* src4 = (const f4*)((tab ? temb : feats)
                                 + ((size_t)b * 64 + c0) * N);
    f4* lds4 = (f4*)row;
    #pragma unroll
    for (int i = 0; i < 8; ++i)
        lds4[i * 512 + t] = src4[i * 512 + t];
    __syncthreads();

    const size_t cs = (size_t)M * K;
    float* o0 = tab ? (out2 + ((size_t)b * 64 + c0) * cs)
                    : (out1 + ((size_t)b * 67 + 3 + c0) * cs);
    f4* o0v = (f4*)o0;
    f4* o1v = (f4*)(o0 + cs);
    const i4* idx4 = (const i4*)(idx + (size_t)b * M * K);

    // 65536 positions, 4 per thread per iter, 512 threads -> 32 iters.
    // One-deep idx prefetch to hide the (L2-resident) index load.
    i4 nn = idx4[t];
    for (int it = 0; it < 32; ++it) {
        const int q = it * 512 + t;     // int4 / float4 position index
        const i4 cur = nn;
        if (it < 31) nn = idx4[q + 512];
        f4 v0, v1;
        v0.x = row[cur.x];     v0.y = row[cur.y];
        v0.z = row[cur.z];     v0.w = row[cur.w];
        v1.x = row[N + cur.x]; v1.y = row[N + cur.y];
        v1.z = row[N + cur.z]; v1.w = row[N + cur.w];
        o0v[q] = v0;
        o1v[q] = v1;
    }
}

extern "C" void kernel_launch(void* const* d_in, const int* in_sizes, int n_in,
                              void* d_out, int out_size, void* d_ws, size_t ws_size,
                              hipStream_t stream) {
    const float* points  = (const float*)d_in[0];  // [8,3,8192]
    const float* centers = (const float*)d_in[1];  // [8,3,2048]
    const float* temb    = (const float*)d_in[2];  // [8,64,8192]
    const float* feats   = (const float*)d_in[3];  // [8,64,8192]

    // workspace layout (2 MB)
    int* idxws = (int*)d_ws;                              // [8,2048,32]

    float* out1 = (float*)d_out;                          // [8,67,2048,32]
    float* out2 = out1 + (size_t)B * (3 + C) * M * K;     // [8,64,2048,32]

    ballquery_kernel<<<B * (M / 64), 512, 0, stream>>>(points, centers,
                                                       idxws, out1);
    gather_kernel<<<B * 2 * 32, 512, 0, stream>>>(temb, feats, idxws,
                                                  out1, out2);
}